// Round 7
// baseline (257.609 us; speedup 1.0000x reference)
//
#include <hip/hip_runtime.h>

#define Bn   2
#define CIN  64
#define COUT 64
#define Hd   192
#define Wd   192
#define HWd  (Hd*Wd)
#define Kk   9
#define NCh  20
#define NTILE 1152          // 64-px output tiles total

typedef __attribute__((ext_vector_type(8))) short short8;
typedef __attribute__((ext_vector_type(4))) float f32x4;

static __device__ __forceinline__ ushort f2bf(float f) {
    unsigned u = __float_as_uint(f);
    u += 0x7fffu + ((u >> 16) & 1u);        // round-to-nearest-even
    return (ushort)(u >> 16);
}

// ---------------- kT: all layout transforms in one kernel ----------------
__global__ __launch_bounds__(256) void kT(const float* __restrict__ x,
        const float* __restrict__ inLO, const float* __restrict__ outLO,
        const float* __restrict__ w, const float* __restrict__ off_w,
        float* __restrict__ xt, float* __restrict__ inLOt,
        float* __restrict__ outLOt, ushort* __restrict__ wtb,
        float* __restrict__ owt) {
    __shared__ float lds[20 * 257];
    int bid = blockIdx.x, tid = threadIdx.x;
    if (bid < 1152) {                       // x -> xt [b][p][64]
        int b = bid / 576, p0 = (bid % 576) * 64;
        const float* src = x + b * CIN * HWd + p0;
        #pragma unroll
        for (int r = 0; r < 16; ++r) {
            int e = r * 256 + tid;          // e = c*64 + p
            int c = e >> 6, p = e & 63;
            lds[c * 65 + p] = src[c * HWd + p];
        }
        __syncthreads();
        float* dst = xt + (b * HWd + p0) * 64;
        #pragma unroll
        for (int r = 0; r < 16; ++r) {
            int e = r * 256 + tid;          // e = p*64 + c
            int p = e >> 6, c = e & 63;
            dst[e] = lds[c * 65 + p];
        }
    } else if (bid < 1728) {                // LO transposes -> [b][p][20]
        int q = bid - 1152;
        int t = q / 288; q %= 288;
        int b = q / 144, p0 = (q % 144) * 256;
        const float* src = (t == 0 ? inLO : outLO) + b * NCh * HWd + p0;
        float* dst = (t == 0 ? inLOt : outLOt) + b * NCh * HWd + p0 * NCh;
        #pragma unroll
        for (int r = 0; r < 20; ++r) {
            int e = r * 256 + tid;          // e = n*256 + p
            int n = e >> 8, p = e & 255;
            lds[n * 257 + p] = src[n * HWd + p];
        }
        __syncthreads();
        #pragma unroll
        for (int r = 0; r < 20; ++r) {
            int e = r * 256 + tid;          // e = p*20 + n
            int p = e / 20, n = e % 20;
            dst[e] = lds[n * 257 + p];
        }
    } else if (bid < 1872) {                // weight -> wtb bf16 B-fragment order
        int f = (bid - 1728) * 256 + tid;   // [tap][nt4][kt2][lane64][e8]
        int e = f & 7, lane = (f >> 3) & 63;
        int kt = (f >> 9) & 1, nt = (f >> 10) & 3, tap = f >> 12;
        int o = nt * 16 + (lane & 15);
        int c = kt * 32 + (lane >> 4) * 8 + e;
        wtb[f] = f2bf(w[(o * CIN + c) * Kk + tap]);
    } else {                                // off_w -> owt [c][tap][oc]
        int idx = (bid - 1872) * 256 + tid;
        if (idx < 18 * 576) {
            int oc = idx % 18, ct = idx / 18;
            int c = ct / 9, tap = ct % 9;
            owt[idx] = off_w[(oc * CIN + c) * Kk + tap];
        }
    }
}

// ---------------- k1: offset conv (3x3, 64->18, pad 1) ----------------
__global__ __launch_bounds__(256) void k1_offset_conv(const float* __restrict__ x,
        const float* __restrict__ owt, const float* __restrict__ off_b,
        float* __restrict__ off) {
    int tid = threadIdx.x;
    int half = blockIdx.x & 1;
    int oc0 = half * 9;
    int pix = (blockIdx.x >> 1) * 256 + tid;
    int b = pix / HWd, pp = pix % HWd;
    int jj = pp % Wd, ii = pp / Wd;
    float acc[9];
    #pragma unroll
    for (int q = 0; q < 9; ++q) acc[q] = off_b[oc0 + q];
    const float* xb = x + b * CIN * HWd;
    for (int c = 0; c < CIN; ++c) {
        const float* xc = xb + c * HWd;
        float v[9];
        #pragma unroll
        for (int dy = 0; dy < 3; ++dy) {
            int yy = ii + dy - 1;
            bool vy = (yy >= 0 && yy < Hd);
            #pragma unroll
            for (int dx = 0; dx < 3; ++dx) {
                int xx = jj + dx - 1;
                bool ok = vy && (xx >= 0) && (xx < Wd);
                int yc = min(max(yy, 0), Hd - 1);
                int xc2 = min(max(xx, 0), Wd - 1);
                float t = xc[yc * Wd + xc2];
                v[dy * 3 + dx] = ok ? t : 0.f;
            }
        }
        const float* wrow = owt + c * 9 * 18 + oc0;
        #pragma unroll
        for (int tap = 0; tap < 9; ++tap) {
            #pragma unroll
            for (int q = 0; q < 9; ++q)
                acc[q] += v[tap] * wrow[tap * 18 + q];
        }
    }
    float* op = off + b * 18 * HWd + pp;
    #pragma unroll
    for (int q = 0; q < 9; ++q) op[(oc0 + q) * HWd] = acc[q];
}

// ---------------- k2: mask via border-clamped bilinear + NC-dot ----------------
__global__ __launch_bounds__(256) void k2_mask(const float* __restrict__ inLOt,
        const float* __restrict__ outLOt, const float* __restrict__ off,
        float* __restrict__ mask) {
    int t = blockIdx.x * 256 + threadIdx.x;     // (b,k,i,j)
    int p = t % HWd;
    int k = (t / HWd) % Kk;
    int b = t / (Kk * HWd);
    int j = p % Wd, i = p / Wd;
    float offy = off[(b * 18 + 2 * k) * HWd + p];
    float offx = off[(b * 18 + 2 * k + 1) * HWd + p];
    float py = (float)(i + (k / 3)) + offy - 95.5f;
    float px = (float)(j + (k % 3)) + offx - 95.5f;
    py = fminf(fmaxf(py, 0.f), 191.f);
    px = fminf(fmaxf(px, 0.f), 191.f);
    float y0f = floorf(py), x0f = floorf(px);
    float ly = py - y0f, lx = px - x0f;
    int y0 = (int)y0f, x0 = (int)x0f;
    int y1 = min(y0 + 1, Hd - 1), x1 = min(x0 + 1, Wd - 1);
    float w00 = (1.f - ly) * (1.f - lx);
    float w01 = (1.f - ly) * lx;
    float w10 = ly * (1.f - lx);
    float w11 = ly * lx;
    const float4* L00 = (const float4*)(inLOt + (b * HWd + y0 * Wd + x0) * NCh);
    const float4* L01 = (const float4*)(inLOt + (b * HWd + y0 * Wd + x1) * NCh);
    const float4* L10 = (const float4*)(inLOt + (b * HWd + y1 * Wd + x0) * NCh);
    const float4* L11 = (const float4*)(inLOt + (b * HWd + y1 * Wd + x1) * NCh);
    const float4* O   = (const float4*)(outLOt + (b * HWd + p) * NCh);
    float acc = 0.f;
    #pragma unroll
    for (int n = 0; n < 5; ++n) {
        float4 a = L00[n], bb = L01[n], c = L10[n], d = L11[n], o = O[n];
        acc += (w00 * a.x + w01 * bb.x + w10 * c.x + w11 * d.x) * o.x;
        acc += (w00 * a.y + w01 * bb.y + w10 * c.y + w11 * d.y) * o.y;
        acc += (w00 * a.z + w01 * bb.z + w10 * c.z + w11 * d.z) * o.z;
        acc += (w00 * a.w + w01 * bb.w + w10 * c.w + w11 * d.w) * o.w;
    }
    mask[(b * Kk + k) * HWd + p] = acc;
}

// ---------------- k3: deformable conv, bf16 MFMA GEMM, tap-split x2 ----------------
// grid = 2*NTILE. h = bid/NTILE selects taps [0,5) or [5,9); tb = bid%NTILE.
// Partial f32 tile written to part[h][tb][o*64+p] (no bias here).
__global__ __launch_bounds__(256) void k3_part(const float* __restrict__ xt,
        const float* __restrict__ off, const float* __restrict__ mask,
        const ushort* __restrict__ wtb, float* __restrict__ part) {
    __shared__ __align__(16) ushort A_lds[4 * 2 * 64 * 8];   // 8 KB
    int tid = threadIdx.x;
    int bid = blockIdx.x;
    int h = bid >= NTILE;           // same XCD for both halves (NTILE%8==0)
    int tb = bid - (h ? NTILE : 0);
    int t0 = h ? 5 : 0, t1 = h ? 9 : 5;
    int jt = tb % 3, i = (tb / 3) % Hd, b = tb / (3 * Hd);
    int j0 = jt * 64;

    int lane = tid & 63;
    int wv_id = tid >> 6;
    int wm = wv_id >> 1;            // m32 tile
    int wn = wv_id & 1;             // n32 tile

    int pA = tid & 63;              // pixel this thread stages
    int cg = tid >> 6;              // channel quarter (16 ch)
    int pix = i * Wd + j0 + pA;
    const float4* x4 = (const float4*)(xt + (size_t)b * HWd * 64);

    f32x4 acc[2][2];
    #pragma unroll
    for (int mi = 0; mi < 2; ++mi)
        #pragma unroll
        for (int ni = 0; ni < 2; ++ni)
            acc[mi][ni] = (f32x4){0.f, 0.f, 0.f, 0.f};

    int mt_w = pA >> 4, row_w = pA & 15, kt_w = cg >> 1;   // A-write coords

    for (int t = t0; t < t1; ++t) {
        // B fragments: global fragment-ordered bf16, lane-linear (L2-hit)
        short8 bf[2][2];
        #pragma unroll
        for (int kt = 0; kt < 2; ++kt)
            #pragma unroll
            for (int ni = 0; ni < 2; ++ni) {
                int nt = wn * 2 + ni;
                bf[kt][ni] = *(const short8*)(wtb +
                    ((((t * 4 + nt) * 2 + kt) * 64 + lane) << 3));
            }

        // per-thread tap computation
        float offy = off[(b * 18 + 2 * t) * HWd + pix];
        float offx = off[(b * 18 + 2 * t + 1) * HWd + pix];
        float m = mask[(b * Kk + t) * HWd + pix];
        float py = (float)(i - 1 + (t / 3)) + offy;
        float px = (float)(j0 + pA - 1 + (t % 3)) + offx;
        float y0f = floorf(py), x0f = floorf(px);
        float ly = py - y0f, lx = px - x0f;
        int y0 = (int)y0f, x0 = (int)x0f;
        int y1 = y0 + 1, x1 = x0 + 1;
        bool vy0 = (y0 >= 0 && y0 < Hd), vy1 = (y1 >= 0 && y1 < Hd);
        bool vx0 = (x0 >= 0 && x0 < Wd), vx1 = (x1 >= 0 && x1 < Wd);
        float w00 = (vy0 && vx0) ? (1.f - ly) * (1.f - lx) * m : 0.f;
        float w01 = (vy0 && vx1) ? (1.f - ly) * lx * m : 0.f;
        float w10 = (vy1 && vx0) ? ly * (1.f - lx) * m : 0.f;
        float w11 = (vy1 && vx1) ? ly * lx * m : 0.f;
        int y0c = min(max(y0, 0), Hd - 1), y1c = min(max(y1, 0), Hd - 1);
        int x0c = min(max(x0, 0), Wd - 1), x1c = min(max(x1, 0), Wd - 1);
        int i00 = (y0c * Wd + x0c) * 16 + cg * 4;   // float4 units
        int i01 = (y0c * Wd + x1c) * 16 + cg * 4;
        int i10 = (y1c * Wd + x0c) * 16 + cg * 4;
        int i11 = (y1c * Wd + x1c) * 16 + cg * 4;

        ushort sv[16];
        #pragma unroll
        for (int g = 0; g < 4; ++g) {
            float4 g00 = x4[i00 + g];
            float4 g01 = x4[i01 + g];
            float4 g10 = x4[i10 + g];
            float4 g11 = x4[i11 + g];
            sv[g * 4 + 0] = f2bf(w00 * g00.x + w01 * g01.x + w10 * g10.x + w11 * g11.x);
            sv[g * 4 + 1] = f2bf(w00 * g00.y + w01 * g01.y + w10 * g10.y + w11 * g11.y);
            sv[g * 4 + 2] = f2bf(w00 * g00.z + w01 * g01.z + w10 * g10.z + w11 * g11.z);
            sv[g * 4 + 3] = f2bf(w00 * g00.w + w01 * g01.w + w10 * g10.w + w11 * g11.w);
        }
        #pragma unroll
        for (int hh = 0; hh < 2; ++hh) {
            short8 pk;
            #pragma unroll
            for (int e = 0; e < 8; ++e) pk[e] = (short)sv[hh * 8 + e];
            int lw = ((cg & 1) * 2 + hh) * 16 + row_w;
            *(short8*)&A_lds[(((mt_w * 2 + kt_w) * 64 + lw) << 3)] = pk;
        }
        __syncthreads();

        #pragma unroll
        for (int kt = 0; kt < 2; ++kt) {
            #pragma unroll
            for (int mi = 0; mi < 2; ++mi) {
                int mt2 = wm * 2 + mi;
                short8 af = *(const short8*)&A_lds[(((mt2 * 2 + kt) * 64 + lane) << 3)];
                acc[mi][0] = __builtin_amdgcn_mfma_f32_16x16x32_bf16(
                                 af, bf[kt][0], acc[mi][0], 0, 0, 0);
                acc[mi][1] = __builtin_amdgcn_mfma_f32_16x16x32_bf16(
                                 af, bf[kt][1], acc[mi][1], 0, 0, 0);
            }
        }
        __syncthreads();
    }

    // write partial tile: part[(h*NTILE+tb)*4096 + o*64 + p], float4 on p
    float* pb = part + ((size_t)(h * NTILE + tb) << 12);
    int colo = lane & 15;
    int rb = (lane >> 4) * 4;
    #pragma unroll
    for (int ni = 0; ni < 2; ++ni) {
        int o = wn * 32 + ni * 16 + colo;
        #pragma unroll
        for (int mi = 0; mi < 2; ++mi) {
            int p0 = wm * 32 + mi * 16 + rb;
            float4 r;
            r.x = acc[mi][ni][0];
            r.y = acc[mi][ni][1];
            r.z = acc[mi][ni][2];
            r.w = acc[mi][ni][3];
            *(float4*)(pb + o * 64 + p0) = r;
        }
    }
}

// ---------------- k4: reduce halves + bias -> out ----------------
__global__ __launch_bounds__(256) void k4_reduce(const float* __restrict__ part,
        const float* __restrict__ bias, float* __restrict__ out) {
    int e4 = blockIdx.x * 256 + threadIdx.x;    // float4 index, NTILE*1024 total
    int tile = e4 >> 10;
    int wi = e4 & 1023;
    int o = wi >> 4;
    int p0 = (wi & 15) << 2;
    const float4* pp = (const float4*)part;
    float4 a = pp[e4];
    float4 c = pp[e4 + NTILE * 1024];
    float bv = bias[o];
    int jt = tile % 3, i = (tile / 3) % Hd, b = tile / (3 * Hd);
    float4 r;
    r.x = a.x + c.x + bv;
    r.y = a.y + c.y + bv;
    r.z = a.z + c.z + bv;
    r.w = a.w + c.w + bv;
    *(float4*)(out + ((size_t)(b * COUT + o) * HWd) + i * Wd + jt * 64 + p0) = r;
}

extern "C" void kernel_launch(void* const* d_in, const int* in_sizes, int n_in,
                              void* d_out, int out_size, void* d_ws, size_t ws_size,
                              hipStream_t stream) {
    const float* x      = (const float*)d_in[0];
    const float* inLO   = (const float*)d_in[1];
    const float* outLO  = (const float*)d_in[2];
    const float* weight = (const float*)d_in[3];
    const float* bias   = (const float*)d_in[4];
    const float* off_w  = (const float*)d_in[5];
    const float* off_b  = (const float*)d_in[6];
    float* out = (float*)d_out;

    float*  off    = (float*)d_ws;                      // 2*18*36864
    float*  mask   = off    + Bn * 18 * HWd;            // 2*9*36864
    ushort* wtb    = (ushort*)(mask + Bn * Kk * HWd);   // 36864 bf16
    float*  owt    = (float*)(mask + Bn * Kk * HWd) + Kk * CIN * COUT;
    float*  xt     = owt    + 576 * 18;                 // 2*36864*64
    float*  inLOt  = xt     + (size_t)Bn * HWd * CIN;
    float*  outLOt = inLOt  + (size_t)Bn * HWd * NCh;
    float*  part   = outLOt + (size_t)Bn * HWd * NCh;   // 2*1152*4096

    kT<<<1913, 256, 0, stream>>>(x, inLO, outLO, weight, off_w,
                                 xt, inLOt, outLOt, wtb, owt);
    k1_offset_conv<<<576, 256, 0, stream>>>(x, owt, off_b, off);
    k2_mask<<<2592, 256, 0, stream>>>(inLOt, outLOt, off, mask);
    k3_part<<<2 * NTILE, 256, 0, stream>>>(xt, off, mask, wtb, part);
    k4_reduce<<<4608, 256, 0, stream>>>(part, bias, out);
}

// Round 8
// 209.190 us; speedup vs baseline: 1.2315x; 1.2315x over previous
//
#include <hip/hip_runtime.h>

#define Bn   2
#define CIN  64
#define COUT 64
#define Hd   192
#define Wd   192
#define HWd  (Hd*Wd)
#define Kk   9
#define NCh  20
#define NTILE 1152          // 64-px output tiles total

typedef __attribute__((ext_vector_type(8))) short short8;
typedef __attribute__((ext_vector_type(4))) float f32x4;

static __device__ __forceinline__ ushort f2bf(float f) {
    unsigned u = __float_as_uint(f);
    u += 0x7fffu + ((u >> 16) & 1u);        // round-to-nearest-even
    return (ushort)(u >> 16);
}
static __device__ __forceinline__ float bf2f(ushort v) {
    return __uint_as_float(((unsigned)v) << 16);
}

// ---------------- kT: all layout transforms in one kernel ----------------
__global__ __launch_bounds__(256) void kT(const float* __restrict__ x,
        const float* __restrict__ inLO, const float* __restrict__ outLO,
        const float* __restrict__ w, const float* __restrict__ off_w,
        ushort* __restrict__ xtb, float* __restrict__ inLOt,
        float* __restrict__ outLOt, ushort* __restrict__ wtb,
        float* __restrict__ owt) {
    __shared__ float lds[20 * 257];
    int bid = blockIdx.x, tid = threadIdx.x;
    if (bid < 1152) {                       // x -> xtb [b][p][64] bf16
        int b = bid / 576, p0 = (bid % 576) * 64;
        const float* src = x + b * CIN * HWd + p0;
        #pragma unroll
        for (int r = 0; r < 16; ++r) {
            int e = r * 256 + tid;          // e = c*64 + p
            int c = e >> 6, p = e & 63;
            lds[c * 65 + p] = src[c * HWd + p];
        }
        __syncthreads();
        ushort* dst = xtb + ((size_t)(b * HWd + p0)) * 64;
        #pragma unroll
        for (int r = 0; r < 16; ++r) {
            int e = r * 256 + tid;          // e = p*64 + c
            int p = e >> 6, c = e & 63;
            dst[e] = f2bf(lds[c * 65 + p]);
        }
    } else if (bid < 1728) {                // LO transposes -> [b][p][20]
        int q = bid - 1152;
        int t = q / 288; q %= 288;
        int b = q / 144, p0 = (q % 144) * 256;
        const float* src = (t == 0 ? inLO : outLO) + b * NCh * HWd + p0;
        float* dst = (t == 0 ? inLOt : outLOt) + b * NCh * HWd + p0 * NCh;
        #pragma unroll
        for (int r = 0; r < 20; ++r) {
            int e = r * 256 + tid;          // e = n*256 + p
            int n = e >> 8, p = e & 255;
            lds[n * 257 + p] = src[n * HWd + p];
        }
        __syncthreads();
        #pragma unroll
        for (int r = 0; r < 20; ++r) {
            int e = r * 256 + tid;          // e = p*20 + n
            int p = e / 20, n = e % 20;
            dst[e] = lds[n * 257 + p];
        }
    } else if (bid < 1872) {                // weight -> wtb bf16 B-fragment order
        int f = (bid - 1728) * 256 + tid;   // [tap][nt4][kt2][lane64][e8]
        int e = f & 7, lane = (f >> 3) & 63;
        int kt = (f >> 9) & 1, nt = (f >> 10) & 3, tap = f >> 12;
        int o = nt * 16 + (lane & 15);
        int c = kt * 32 + (lane >> 4) * 8 + e;
        wtb[f] = f2bf(w[(o * CIN + c) * Kk + tap]);
    } else {                                // off_w -> owt [c][tap][oc]
        int idx = (bid - 1872) * 256 + tid;
        if (idx < 18 * 576) {
            int oc = idx % 18, ct = idx / 18;
            int c = ct / 9, tap = ct % 9;
            owt[idx] = off_w[(oc * CIN + c) * Kk + tap];
        }
    }
}

// ---------------- k1: offset conv (3x3, 64->18, pad 1) ----------------
__global__ __launch_bounds__(256) void k1_offset_conv(const float* __restrict__ x,
        const float* __restrict__ owt, const float* __restrict__ off_b,
        float* __restrict__ off) {
    int tid = threadIdx.x;
    int half = blockIdx.x & 1;
    int oc0 = half * 9;
    int pix = (blockIdx.x >> 1) * 256 + tid;
    int b = pix / HWd, pp = pix % HWd;
    int jj = pp % Wd, ii = pp / Wd;
    float acc[9];
    #pragma unroll
    for (int q = 0; q < 9; ++q) acc[q] = off_b[oc0 + q];
    const float* xb = x + b * CIN * HWd;
    for (int c = 0; c < CIN; ++c) {
        const float* xc = xb + c * HWd;
        float v[9];
        #pragma unroll
        for (int dy = 0; dy < 3; ++dy) {
            int yy = ii + dy - 1;
            bool vy = (yy >= 0 && yy < Hd);
            #pragma unroll
            for (int dx = 0; dx < 3; ++dx) {
                int xx = jj + dx - 1;
                bool ok = vy && (xx >= 0) && (xx < Wd);
                int yc = min(max(yy, 0), Hd - 1);
                int xc2 = min(max(xx, 0), Wd - 1);
                float t = xc[yc * Wd + xc2];
                v[dy * 3 + dx] = ok ? t : 0.f;
            }
        }
        const float* wrow = owt + c * 9 * 18 + oc0;
        #pragma unroll
        for (int tap = 0; tap < 9; ++tap) {
            #pragma unroll
            for (int q = 0; q < 9; ++q)
                acc[q] += v[tap] * wrow[tap * 18 + q];
        }
    }
    float* op = off + b * 18 * HWd + pp;
    #pragma unroll
    for (int q = 0; q < 9; ++q) op[(oc0 + q) * HWd] = acc[q];
}

// ---------------- k2: mask via border-clamped bilinear + NC-dot ----------------
__global__ __launch_bounds__(256) void k2_mask(const float* __restrict__ inLOt,
        const float* __restrict__ outLOt, const float* __restrict__ off,
        float* __restrict__ mask) {
    int t = blockIdx.x * 256 + threadIdx.x;     // (b,k,i,j)
    int p = t % HWd;
    int k = (t / HWd) % Kk;
    int b = t / (Kk * HWd);
    int j = p % Wd, i = p / Wd;
    float offy = off[(b * 18 + 2 * k) * HWd + p];
    float offx = off[(b * 18 + 2 * k + 1) * HWd + p];
    float py = (float)(i + (k / 3)) + offy - 95.5f;
    float px = (float)(j + (k % 3)) + offx - 95.5f;
    py = fminf(fmaxf(py, 0.f), 191.f);
    px = fminf(fmaxf(px, 0.f), 191.f);
    float y0f = floorf(py), x0f = floorf(px);
    float ly = py - y0f, lx = px - x0f;
    int y0 = (int)y0f, x0 = (int)x0f;
    int y1 = min(y0 + 1, Hd - 1), x1 = min(x0 + 1, Wd - 1);
    float w00 = (1.f - ly) * (1.f - lx);
    float w01 = (1.f - ly) * lx;
    float w10 = ly * (1.f - lx);
    float w11 = ly * lx;
    const float4* L00 = (const float4*)(inLOt + (b * HWd + y0 * Wd + x0) * NCh);
    const float4* L01 = (const float4*)(inLOt + (b * HWd + y0 * Wd + x1) * NCh);
    const float4* L10 = (const float4*)(inLOt + (b * HWd + y1 * Wd + x0) * NCh);
    const float4* L11 = (const float4*)(inLOt + (b * HWd + y1 * Wd + x1) * NCh);
    const float4* O   = (const float4*)(outLOt + (b * HWd + p) * NCh);
    float acc = 0.f;
    #pragma unroll
    for (int n = 0; n < 5; ++n) {
        float4 a = L00[n], bb = L01[n], c = L10[n], d = L11[n], o = O[n];
        acc += (w00 * a.x + w01 * bb.x + w10 * c.x + w11 * d.x) * o.x;
        acc += (w00 * a.y + w01 * bb.y + w10 * c.y + w11 * d.y) * o.y;
        acc += (w00 * a.z + w01 * bb.z + w10 * c.z + w11 * d.z) * o.z;
        acc += (w00 * a.w + w01 * bb.w + w10 * c.w + w11 * d.w) * o.w;
    }
    mask[(b * Kk + k) * HWd + p] = acc;
}

// ---------------- k3: deformable conv, bf16 MFMA GEMM, coalesced gathers ----------------
// grid = 2*NTILE, tap-split. Staging: lane = chunk*8 + px_octet:
// one instr = 8 consecutive px x one 16B chunk -> 16 distinct 128B-lines.
__global__ __launch_bounds__(256) void k3_part(const ushort* __restrict__ xtb,
        const float* __restrict__ off, const float* __restrict__ mask,
        const ushort* __restrict__ wtb, float* __restrict__ part) {
    __shared__ __align__(16) ushort A_lds[4 * 2 * 64 * 8];   // 8 KB
    int tid = threadIdx.x;
    int bid = blockIdx.x;
    int h = bid >= NTILE;           // taps [0,5) or [5,9)
    int tb = bid - (h ? NTILE : 0);
    int t0 = h ? 5 : 0, t1 = h ? 9 : 5;
    int jt = tb % 3, i = (tb / 3) % Hd, b = tb / (3 * Hd);
    int j0 = jt * 64;

    int lane = tid & 63;
    int wv_id = tid >> 6;
    int wm = wv_id >> 1;            // m32 tile for MFMA
    int wn = wv_id & 1;             // n32 tile for MFMA

    int pxo = lane & 7;             // pixel within octet
    int chunk = lane >> 3;          // 16B chunk (8 bf16 ch), 0..7
    int kt_s = chunk >> 2;          // staging kt
    int ksub = chunk & 3;           // staging k-sub
    const ushort* xb = xtb + (size_t)b * HWd * 64;

    f32x4 acc[2][2];
    #pragma unroll
    for (int mi = 0; mi < 2; ++mi)
        #pragma unroll
        for (int ni = 0; ni < 2; ++ni)
            acc[mi][ni] = (f32x4){0.f, 0.f, 0.f, 0.f};

    for (int t = t0; t < t1; ++t) {
        // B fragments: global fragment-ordered bf16, lane-linear (L2-hit)
        short8 bf[2][2];
        #pragma unroll
        for (int kt = 0; kt < 2; ++kt)
            #pragma unroll
            for (int ni = 0; ni < 2; ++ni) {
                int nt = wn * 2 + ni;
                bf[kt][ni] = *(const short8*)(wtb +
                    ((((t * 4 + nt) * 2 + kt) * 64 + lane) << 3));
            }

        // stage A: 2 rounds of 8 px (wave owns px [wv_id*16, wv_id*16+16))
        #pragma unroll
        for (int r = 0; r < 2; ++r) {
            int px_loc = (wv_id << 4) + (r << 3) + pxo;
            int pix = i * Wd + j0 + px_loc;
            float offy = off[(b * 18 + 2 * t) * HWd + pix];
            float offx = off[(b * 18 + 2 * t + 1) * HWd + pix];
            float m = mask[(b * Kk + t) * HWd + pix];
            float py = (float)(i - 1 + (t / 3)) + offy;
            float px = (float)(j0 + px_loc - 1 + (t % 3)) + offx;
            float y0f = floorf(py), x0f = floorf(px);
            float ly = py - y0f, lx = px - x0f;
            int y0 = (int)y0f, x0 = (int)x0f;
            int y1 = y0 + 1, x1 = x0 + 1;
            bool vy0 = (y0 >= 0 && y0 < Hd), vy1 = (y1 >= 0 && y1 < Hd);
            bool vx0 = (x0 >= 0 && x0 < Wd), vx1 = (x1 >= 0 && x1 < Wd);
            float w00 = (vy0 && vx0) ? (1.f - ly) * (1.f - lx) * m : 0.f;
            float w01 = (vy0 && vx1) ? (1.f - ly) * lx * m : 0.f;
            float w10 = (vy1 && vx0) ? ly * (1.f - lx) * m : 0.f;
            float w11 = (vy1 && vx1) ? ly * lx * m : 0.f;
            int y0c = min(max(y0, 0), Hd - 1), y1c = min(max(y1, 0), Hd - 1);
            int x0c = min(max(x0, 0), Wd - 1), x1c = min(max(x1, 0), Wd - 1);
            // 4 coalesced 16B gathers: 8 px octet x 128B pixel rows
            const short8* g0p = (const short8*)(xb + (size_t)(y0c * Wd + x0c) * 64 + chunk * 8);
            const short8* g1p = (const short8*)(xb + (size_t)(y0c * Wd + x1c) * 64 + chunk * 8);
            const short8* g2p = (const short8*)(xb + (size_t)(y1c * Wd + x0c) * 64 + chunk * 8);
            const short8* g3p = (const short8*)(xb + (size_t)(y1c * Wd + x1c) * 64 + chunk * 8);
            short8 g0 = *g0p, g1 = *g1p, g2 = *g2p, g3 = *g3p;
            short8 pk;
            #pragma unroll
            for (int e = 0; e < 8; ++e) {
                float s = w00 * bf2f((ushort)g0[e]) + w01 * bf2f((ushort)g1[e])
                        + w10 * bf2f((ushort)g2[e]) + w11 * bf2f((ushort)g3[e]);
                pk[e] = (short)f2bf(s);
            }
            // A-fragment write: consecutive-idx b128 (conflict-free pattern)
            *(short8*)&A_lds[(((wv_id * 2 + kt_s) * 64 + ksub * 16 +
                               ((r << 3) + pxo)) << 3)] = pk;
        }
        __syncthreads();

        #pragma unroll
        for (int kt = 0; kt < 2; ++kt) {
            #pragma unroll
            for (int mi = 0; mi < 2; ++mi) {
                int mt2 = wm * 2 + mi;
                short8 af = *(const short8*)&A_lds[(((mt2 * 2 + kt) * 64 + lane) << 3)];
                acc[mi][0] = __builtin_amdgcn_mfma_f32_16x16x32_bf16(
                                 af, bf[kt][0], acc[mi][0], 0, 0, 0);
                acc[mi][1] = __builtin_amdgcn_mfma_f32_16x16x32_bf16(
                                 af, bf[kt][1], acc[mi][1], 0, 0, 0);
            }
        }
        __syncthreads();
    }

    // write partial tile: part[(h*NTILE+tb)*4096 + o*64 + p], float4 on p
    float* pb = part + ((size_t)(h * NTILE + tb) << 12);
    int colo = lane & 15;
    int rb = (lane >> 4) * 4;
    #pragma unroll
    for (int ni = 0; ni < 2; ++ni) {
        int o = wn * 32 + ni * 16 + colo;
        #pragma unroll
        for (int mi = 0; mi < 2; ++mi) {
            int p0 = wm * 32 + mi * 16 + rb;
            float4 r;
            r.x = acc[mi][ni][0];
            r.y = acc[mi][ni][1];
            r.z = acc[mi][ni][2];
            r.w = acc[mi][ni][3];
            *(float4*)(pb + o * 64 + p0) = r;
        }
    }
}

// ---------------- k4: reduce halves + bias -> out ----------------
__global__ __launch_bounds__(256) void k4_reduce(const float* __restrict__ part,
        const float* __restrict__ bias, float* __restrict__ out) {
    int e4 = blockIdx.x * 256 + threadIdx.x;    // float4 index, NTILE*1024 total
    int tile = e4 >> 10;
    int wi = e4 & 1023;
    int o = wi >> 4;
    int p0 = (wi & 15) << 2;
    const float4* pp = (const float4*)part;
    float4 a = pp[e4];
    float4 c = pp[e4 + NTILE * 1024];
    float bv = bias[o];
    int jt = tile % 3, i = (tile / 3) % Hd, b = tile / (3 * Hd);
    float4 r;
    r.x = a.x + c.x + bv;
    r.y = a.y + c.y + bv;
    r.z = a.z + c.z + bv;
    r.w = a.w + c.w + bv;
    *(float4*)(out + ((size_t)(b * COUT + o) * HWd) + i * Wd + jt * 64 + p0) = r;
}

extern "C" void kernel_launch(void* const* d_in, const int* in_sizes, int n_in,
                              void* d_out, int out_size, void* d_ws, size_t ws_size,
                              hipStream_t stream) {
    const float* x      = (const float*)d_in[0];
    const float* inLO   = (const float*)d_in[1];
    const float* outLO  = (const float*)d_in[2];
    const float* weight = (const float*)d_in[3];
    const float* bias   = (const float*)d_in[4];
    const float* off_w  = (const float*)d_in[5];
    const float* off_b  = (const float*)d_in[6];
    float* out = (float*)d_out;

    float*  off    = (float*)d_ws;                      // 2*18*36864
    float*  mask   = off    + Bn * 18 * HWd;            // 2*9*36864
    ushort* wtb    = (ushort*)(mask + Bn * Kk * HWd);   // 36864 bf16
    float*  owt    = (float*)(mask + Bn * Kk * HWd) + Kk * CIN * COUT;
    ushort* xtb    = (ushort*)(owt + 576 * 18);         // 2*36864*64 bf16
    float*  inLOt  = (float*)(xtb + (size_t)Bn * HWd * CIN);
    float*  outLOt = inLOt  + (size_t)Bn * HWd * NCh;
    float*  part   = outLOt + (size_t)Bn * HWd * NCh;   // 2*1152*4096

    kT<<<1913, 256, 0, stream>>>(x, inLO, outLO, weight, off_w,
                                 xtb, inLOt, outLOt, wtb, owt);
    k1_offset_conv<<<576, 256, 0, stream>>>(x, owt, off_b, off);
    k2_mask<<<2592, 256, 0, stream>>>(inLOt, outLOt, off, mask);
    k3_part<<<2 * NTILE, 256, 0, stream>>>(xtb, off, mask, wtb, part);
    k4_reduce<<<4608, 256, 0, stream>>>(part, bias, out);
}

// Round 9
// 174.553 us; speedup vs baseline: 1.4758x; 1.1984x over previous
//
#include <hip/hip_runtime.h>

#define Bn   2
#define CIN  64
#define COUT 64
#define Hd   192
#define Wd   192
#define HWd  (Hd*Wd)
#define Kk   9
#define NCh  20
#define NCP  24             // padded LO channels (bf16, 48B rows)
#define NTILE 1152          // 64-px output tiles total

typedef __attribute__((ext_vector_type(8))) short short8;
typedef __attribute__((ext_vector_type(4))) float f32x4;

static __device__ __forceinline__ ushort f2bf(float f) {
    unsigned u = __float_as_uint(f);
    u += 0x7fffu + ((u >> 16) & 1u);        // round-to-nearest-even
    return (ushort)(u >> 16);
}
static __device__ __forceinline__ float bf2f(ushort v) {
    return __uint_as_float(((unsigned)v) << 16);
}

// ---------------- kT: all layout transforms ----------------
// [0,1152)    : x [b][64][HW] -> xtb [b][HW][64] bf16
// [1152,1728) : in/outLO [b][20][HW] -> [b][HW][24] bf16 (pad 0)
// [1728,1872) : weight -> wtb bf16 B-frag [tap][nt4][kt2][lane][e8]
// [1872,1944) : off_w  -> owtb bf16 B-frag [tap][nt2][kt2][lane][e8] (oc pad 32)
__global__ __launch_bounds__(256) void kT(const float* __restrict__ x,
        const float* __restrict__ inLO, const float* __restrict__ outLO,
        const float* __restrict__ w, const float* __restrict__ off_w,
        ushort* __restrict__ xtb, ushort* __restrict__ inLOb,
        ushort* __restrict__ outLOb, ushort* __restrict__ wtb,
        ushort* __restrict__ owtb) {
    __shared__ float lds[20 * 257];
    int bid = blockIdx.x, tid = threadIdx.x;
    if (bid < 1152) {                       // x -> xtb
        int b = bid / 576, p0 = (bid % 576) * 64;
        const float* src = x + b * CIN * HWd + p0;
        #pragma unroll
        for (int r = 0; r < 16; ++r) {
            int e = r * 256 + tid;          // e = c*64 + p
            int c = e >> 6, p = e & 63;
            lds[c * 65 + p] = src[c * HWd + p];
        }
        __syncthreads();
        ushort* dst = xtb + ((size_t)(b * HWd + p0)) * 64;
        #pragma unroll
        for (int r = 0; r < 16; ++r) {
            int e = r * 256 + tid;          // e = p*64 + c
            int p = e >> 6, c = e & 63;
            dst[e] = f2bf(lds[c * 65 + p]);
        }
    } else if (bid < 1728) {                // LO -> bf16 [b][p][24]
        int q = bid - 1152;
        int t = q / 288; q %= 288;
        int b = q / 144, p0 = (q % 144) * 256;
        const float* src = (t == 0 ? inLO : outLO) + b * NCh * HWd + p0;
        ushort* dst = (t == 0 ? inLOb : outLOb) + ((size_t)(b * HWd + p0)) * NCP;
        #pragma unroll
        for (int r = 0; r < 20; ++r) {
            int e = r * 256 + tid;          // e = n*256 + p
            int n = e >> 8, p = e & 255;
            lds[n * 257 + p] = src[n * HWd + p];
        }
        __syncthreads();
        #pragma unroll
        for (int r = 0; r < 24; ++r) {
            int e = r * 256 + tid;          // e = p*24 + n
            int p = e / NCP, n = e - p * NCP;
            dst[e] = (n < NCh) ? f2bf(lds[n * 257 + p]) : (ushort)0;
        }
    } else if (bid < 1872) {                // weight -> wtb
        int f = (bid - 1728) * 256 + tid;   // [tap][nt4][kt2][lane64][e8]
        int e = f & 7, lane = (f >> 3) & 63;
        int kt = (f >> 9) & 1, nt = (f >> 10) & 3, tap = f >> 12;
        int o = nt * 16 + (lane & 15);
        int c = kt * 32 + (lane >> 4) * 8 + e;
        wtb[f] = f2bf(w[(o * CIN + c) * Kk + tap]);
    } else {                                // off_w -> owtb (oc padded to 32)
        int f = (bid - 1872) * 256 + tid;   // [tap][nt2][kt2][lane64][e8] = 18432
        if (f < 18432) {
            int e = f & 7, lane = (f >> 3) & 63;
            int kt = (f >> 9) & 1, nt = (f >> 10) & 1, tap = f >> 11;
            int oc = nt * 16 + (lane & 15);
            int c = kt * 32 + (lane >> 4) * 8 + e;
            owtb[f] = (oc < 18) ? f2bf(off_w[(oc * CIN + c) * Kk + tap]) : (ushort)0;
        }
    }
}

// ---------------- k1: offset conv as MFMA GEMM ----------------
// grid NTILE; block = 64 px; 4 waves each 16 px x 32 oc (18 valid).
// A-frags loaded straight from xtb (contiguous 64ch rows), B from owtb.
__global__ __launch_bounds__(256) void k1_gemm(const ushort* __restrict__ xtb,
        const ushort* __restrict__ owtb, const float* __restrict__ off_b,
        float* __restrict__ off) {
    int tid = threadIdx.x, bid = blockIdx.x;
    int jt = bid % 3, i = (bid / 3) % Hd, b = bid / (3 * Hd);
    int j0 = jt * 64;
    int lane = tid & 63, wv = tid >> 6;
    int m = lane & 15;             // A-frag row (px within wave tile)
    int ch8 = lane >> 4;           // A-frag k-subgroup
    int j = j0 + wv * 16 + m;      // absolute x of this lane's A row
    const ushort* xb = xtb + (size_t)b * HWd * 64;

    float bv0 = off_b[m];
    float bv1 = (m < 2) ? off_b[16 + m] : 0.f;
    f32x4 acc0 = (f32x4){bv0, bv0, bv0, bv0};
    f32x4 acc1 = (f32x4){bv1, bv1, bv1, bv1};
    short8 zero8 = {0, 0, 0, 0, 0, 0, 0, 0};

    #pragma unroll
    for (int t = 0; t < 9; ++t) {
        int yy = i + t / 3 - 1;
        int xx = j + t % 3 - 1;
        bool ok = (yy >= 0) && (yy < Hd) && (xx >= 0) && (xx < Wd);
        int yc = min(max(yy, 0), Hd - 1), xc = min(max(xx, 0), Wd - 1);
        const ushort* rowp = xb + (size_t)(yc * Wd + xc) * 64 + ch8 * 8;
        short8 a0 = *(const short8*)rowp;
        short8 a1 = *(const short8*)(rowp + 32);
        a0 = ok ? a0 : zero8;
        a1 = ok ? a1 : zero8;
        const ushort* wb = owtb + ((size_t)t << 11);
        short8 b00 = *(const short8*)(wb + (lane << 3));            // nt0 kt0
        short8 b01 = *(const short8*)(wb + 512 + (lane << 3));      // nt0 kt1
        short8 b10 = *(const short8*)(wb + 1024 + (lane << 3));     // nt1 kt0
        short8 b11 = *(const short8*)(wb + 1536 + (lane << 3));     // nt1 kt1
        acc0 = __builtin_amdgcn_mfma_f32_16x16x32_bf16(a0, b00, acc0, 0, 0, 0);
        acc0 = __builtin_amdgcn_mfma_f32_16x16x32_bf16(a1, b01, acc0, 0, 0, 0);
        acc1 = __builtin_amdgcn_mfma_f32_16x16x32_bf16(a0, b10, acc1, 0, 0, 0);
        acc1 = __builtin_amdgcn_mfma_f32_16x16x32_bf16(a1, b11, acc1, 0, 0, 0);
    }

    // D: row(px) = (lane>>4)*4+reg, col(oc) = lane&15
    int prow = j0 + wv * 16 + (lane >> 4) * 4;
    int oc = lane & 15;
    float* ob = off + (size_t)b * 18 * HWd + i * Wd;
    #pragma unroll
    for (int r = 0; r < 4; ++r)
        ob[oc * HWd + prow + r] = acc0[r];
    if (oc < 2) {
        #pragma unroll
        for (int r = 0; r < 4; ++r)
            ob[(16 + oc) * HWd + prow + r] = acc1[r];
    }
}

// ---------------- k2: mask via border-clamped bilinear + NC-dot (bf16 LO) ----------------
__global__ __launch_bounds__(256) void k2_mask(const ushort* __restrict__ inLOb,
        const ushort* __restrict__ outLOb, const float* __restrict__ off,
        float* __restrict__ mask) {
    int t = blockIdx.x * 256 + threadIdx.x;     // (b,k,p)
    int p = t % HWd;
    int k = (t / HWd) % Kk;
    int b = t / (Kk * HWd);
    int j = p % Wd, i = p / Wd;
    float offy = off[(b * 18 + 2 * k) * HWd + p];
    float offx = off[(b * 18 + 2 * k + 1) * HWd + p];
    float py = (float)(i + (k / 3)) + offy - 95.5f;
    float px = (float)(j + (k % 3)) + offx - 95.5f;
    py = fminf(fmaxf(py, 0.f), 191.f);
    px = fminf(fmaxf(px, 0.f), 191.f);
    float y0f = floorf(py), x0f = floorf(px);
    float ly = py - y0f, lx = px - x0f;
    int y0 = (int)y0f, x0 = (int)x0f;
    int y1 = min(y0 + 1, Hd - 1), x1 = min(x0 + 1, Wd - 1);
    float w00 = (1.f - ly) * (1.f - lx);
    float w01 = (1.f - ly) * lx;
    float w10 = ly * (1.f - lx);
    float w11 = ly * lx;
    const short8* L00 = (const short8*)(inLOb + (size_t)(b * HWd + y0 * Wd + x0) * NCP);
    const short8* L01 = (const short8*)(inLOb + (size_t)(b * HWd + y0 * Wd + x1) * NCP);
    const short8* L10 = (const short8*)(inLOb + (size_t)(b * HWd + y1 * Wd + x0) * NCP);
    const short8* L11 = (const short8*)(inLOb + (size_t)(b * HWd + y1 * Wd + x1) * NCP);
    const short8* O  = (const short8*)(outLOb + (size_t)(b * HWd + p) * NCP);
    float acc = 0.f;
    #pragma unroll
    for (int n3 = 0; n3 < 3; ++n3) {
        short8 a = L00[n3], bb = L01[n3], c = L10[n3], d = L11[n3], o = O[n3];
        #pragma unroll
        for (int e = 0; e < 8; ++e) {
            float s = w00 * bf2f((ushort)a[e]) + w01 * bf2f((ushort)bb[e])
                    + w10 * bf2f((ushort)c[e]) + w11 * bf2f((ushort)d[e]);
            acc += s * bf2f((ushort)o[e]);
        }
    }
    mask[(b * Kk + k) * HWd + p] = acc;
}

// ---------------- k3: deformable conv, bf16 MFMA GEMM, coalesced gathers ----------------
__global__ __launch_bounds__(256) void k3_part(const ushort* __restrict__ xtb,
        const float* __restrict__ off, const float* __restrict__ mask,
        const ushort* __restrict__ wtb, float* __restrict__ part) {
    __shared__ __align__(16) ushort A_lds[4 * 2 * 64 * 8];   // 8 KB
    int tid = threadIdx.x;
    int bid = blockIdx.x;
    int h = bid >= NTILE;           // taps [0,5) or [5,9)
    int tb = bid - (h ? NTILE : 0);
    int t0 = h ? 5 : 0, t1 = h ? 9 : 5;
    int jt = tb % 3, i = (tb / 3) % Hd, b = tb / (3 * Hd);
    int j0 = jt * 64;

    int lane = tid & 63;
    int wv_id = tid >> 6;
    int wm = wv_id >> 1;            // m32 tile for MFMA
    int wn = wv_id & 1;             // n32 tile for MFMA

    int pxo = lane & 7;             // pixel within octet
    int chunk = lane >> 3;          // 16B chunk (8 bf16 ch), 0..7
    int kt_s = chunk >> 2;          // staging kt
    int ksub = chunk & 3;           // staging k-sub
    const ushort* xb = xtb + (size_t)b * HWd * 64;

    f32x4 acc[2][2];
    #pragma unroll
    for (int mi = 0; mi < 2; ++mi)
        #pragma unroll
        for (int ni = 0; ni < 2; ++ni)
            acc[mi][ni] = (f32x4){0.f, 0.f, 0.f, 0.f};

    for (int t = t0; t < t1; ++t) {
        short8 bf[2][2];
        #pragma unroll
        for (int kt = 0; kt < 2; ++kt)
            #pragma unroll
            for (int ni = 0; ni < 2; ++ni) {
                int nt = wn * 2 + ni;
                bf[kt][ni] = *(const short8*)(wtb +
                    ((((t * 4 + nt) * 2 + kt) * 64 + lane) << 3));
            }

        #pragma unroll
        for (int r = 0; r < 2; ++r) {
            int px_loc = (wv_id << 4) + (r << 3) + pxo;
            int pix = i * Wd + j0 + px_loc;
            float offy = off[(b * 18 + 2 * t) * HWd + pix];
            float offx = off[(b * 18 + 2 * t + 1) * HWd + pix];
            float m = mask[(b * Kk + t) * HWd + pix];
            float py = (float)(i - 1 + (t / 3)) + offy;
            float px = (float)(j0 + px_loc - 1 + (t % 3)) + offx;
            float y0f = floorf(py), x0f = floorf(px);
            float ly = py - y0f, lx = px - x0f;
            int y0 = (int)y0f, x0 = (int)x0f;
            int y1 = y0 + 1, x1 = x0 + 1;
            bool vy0 = (y0 >= 0 && y0 < Hd), vy1 = (y1 >= 0 && y1 < Hd);
            bool vx0 = (x0 >= 0 && x0 < Wd), vx1 = (x1 >= 0 && x1 < Wd);
            float w00 = (vy0 && vx0) ? (1.f - ly) * (1.f - lx) * m : 0.f;
            float w01 = (vy0 && vx1) ? (1.f - ly) * lx * m : 0.f;
            float w10 = (vy1 && vx0) ? ly * (1.f - lx) * m : 0.f;
            float w11 = (vy1 && vx1) ? ly * lx * m : 0.f;
            int y0c = min(max(y0, 0), Hd - 1), y1c = min(max(y1, 0), Hd - 1);
            int x0c = min(max(x0, 0), Wd - 1), x1c = min(max(x1, 0), Wd - 1);
            const short8* g0p = (const short8*)(xb + (size_t)(y0c * Wd + x0c) * 64 + chunk * 8);
            const short8* g1p = (const short8*)(xb + (size_t)(y0c * Wd + x1c) * 64 + chunk * 8);
            const short8* g2p = (const short8*)(xb + (size_t)(y1c * Wd + x0c) * 64 + chunk * 8);
            const short8* g3p = (const short8*)(xb + (size_t)(y1c * Wd + x1c) * 64 + chunk * 8);
            short8 g0 = *g0p, g1 = *g1p, g2 = *g2p, g3 = *g3p;
            short8 pk;
            #pragma unroll
            for (int e = 0; e < 8; ++e) {
                float s = w00 * bf2f((ushort)g0[e]) + w01 * bf2f((ushort)g1[e])
                        + w10 * bf2f((ushort)g2[e]) + w11 * bf2f((ushort)g3[e]);
                pk[e] = (short)f2bf(s);
            }
            *(short8*)&A_lds[(((wv_id * 2 + kt_s) * 64 + ksub * 16 +
                               ((r << 3) + pxo)) << 3)] = pk;
        }
        __syncthreads();

        #pragma unroll
        for (int kt = 0; kt < 2; ++kt) {
            #pragma unroll
            for (int mi = 0; mi < 2; ++mi) {
                int mt2 = wm * 2 + mi;
                short8 af = *(const short8*)&A_lds[(((mt2 * 2 + kt) * 64 + lane) << 3)];
                acc[mi][0] = __builtin_amdgcn_mfma_f32_16x16x32_bf16(
                                 af, bf[kt][0], acc[mi][0], 0, 0, 0);
                acc[mi][1] = __builtin_amdgcn_mfma_f32_16x16x32_bf16(
                                 af, bf[kt][1], acc[mi][1], 0, 0, 0);
            }
        }
        __syncthreads();
    }

    float* pb = part + ((size_t)(h * NTILE + tb) << 12);
    int colo = lane & 15;
    int rb = (lane >> 4) * 4;
    #pragma unroll
    for (int ni = 0; ni < 2; ++ni) {
        int o = wn * 32 + ni * 16 + colo;
        #pragma unroll
        for (int mi = 0; mi < 2; ++mi) {
            int p0 = wm * 32 + mi * 16 + rb;
            float4 r;
            r.x = acc[mi][ni][0];
            r.y = acc[mi][ni][1];
            r.z = acc[mi][ni][2];
            r.w = acc[mi][ni][3];
            *(float4*)(pb + o * 64 + p0) = r;
        }
    }
}

// ---------------- k4: reduce halves + bias -> out ----------------
__global__ __launch_bounds__(256) void k4_reduce(const float* __restrict__ part,
        const float* __restrict__ bias, float* __restrict__ out) {
    int e4 = blockIdx.x * 256 + threadIdx.x;    // float4 index, NTILE*1024 total
    int tile = e4 >> 10;
    int wi = e4 & 1023;
    int o = wi >> 4;
    int p0 = (wi & 15) << 2;
    const float4* pp = (const float4*)part;
    float4 a = pp[e4];
    float4 c = pp[e4 + NTILE * 1024];
    float bv = bias[o];
    int jt = tile % 3, i = (tile / 3) % Hd, b = tile / (3 * Hd);
    float4 r;
    r.x = a.x + c.x + bv;
    r.y = a.y + c.y + bv;
    r.z = a.z + c.z + bv;
    r.w = a.w + c.w + bv;
    *(float4*)(out + ((size_t)(b * COUT + o) * HWd) + i * Wd + jt * 64 + p0) = r;
}

extern "C" void kernel_launch(void* const* d_in, const int* in_sizes, int n_in,
                              void* d_out, int out_size, void* d_ws, size_t ws_size,
                              hipStream_t stream) {
    const float* x      = (const float*)d_in[0];
    const float* inLO   = (const float*)d_in[1];
    const float* outLO  = (const float*)d_in[2];
    const float* weight = (const float*)d_in[3];
    const float* bias   = (const float*)d_in[4];
    const float* off_w  = (const float*)d_in[5];
    const float* off_b  = (const float*)d_in[6];
    float* out = (float*)d_out;

    float*  off    = (float*)d_ws;                      // 2*18*36864 f
    float*  mask   = off   + Bn * 18 * HWd;             // 2*9*36864 f
    ushort* wtb    = (ushort*)(mask + Bn * Kk * HWd);   // 36864 bf16
    ushort* owtb   = wtb + 36864;                       // 18432 bf16
    ushort* xtb    = owtb + 18432;                      // 2*36864*64 bf16
    ushort* inLOb  = xtb + (size_t)Bn * HWd * CIN;      // 2*36864*24 bf16
    ushort* outLOb = inLOb + (size_t)Bn * HWd * NCP;
    float*  part   = (float*)(outLOb + (size_t)Bn * HWd * NCP);  // 2*1152*4096 f

    kT<<<1944, 256, 0, stream>>>(x, inLO, outLO, weight, off_w,
                                 xtb, inLOb, outLOb, wtb, owtb);
    k1_gemm<<<NTILE, 256, 0, stream>>>(xtb, owtb, off_b, off);
    k2_mask<<<2592, 256, 0, stream>>>(inLOb, outLOb, off, mask);
    k3_part<<<2 * NTILE, 256, 0, stream>>>(xtb, off, mask, wtb, part);
    k4_reduce<<<4608, 256, 0, stream>>>(part, bias, out);
}

// Round 10
// 173.703 us; speedup vs baseline: 1.4830x; 1.0049x over previous
//
#include <hip/hip_runtime.h>
#include <hip/hip_fp16.h>

#define Bn   2
#define CIN  64
#define COUT 64
#define Hd   192
#define Wd   192
#define HWd  (Hd*Wd)
#define Kk   9
#define NCh  20
#define NCP  24             // padded LO channels (bf16, 48B rows)
#define NTILE 1152          // 64-px output tiles total

typedef __attribute__((ext_vector_type(8))) short short8;
typedef __attribute__((ext_vector_type(4))) float f32x4;

static __device__ __forceinline__ ushort f2bf(float f) {
    unsigned u = __float_as_uint(f);
    u += 0x7fffu + ((u >> 16) & 1u);        // round-to-nearest-even
    return (ushort)(u >> 16);
}
static __device__ __forceinline__ float bf2f(ushort v) {
    return __uint_as_float(((unsigned)v) << 16);
}
static __device__ __forceinline__ ushort f2h(float f) {
    return __half_as_ushort(__float2half_rn(f));
}
static __device__ __forceinline__ float h2f(ushort u) {
    return __half2float(__ushort_as_half(u));
}

// ---------------- kT: all layout transforms ----------------
__global__ __launch_bounds__(256) void kT(const float* __restrict__ x,
        const float* __restrict__ inLO, const float* __restrict__ outLO,
        const float* __restrict__ w, const float* __restrict__ off_w,
        ushort* __restrict__ xtb, ushort* __restrict__ inLOb,
        ushort* __restrict__ outLOb, ushort* __restrict__ wtb,
        ushort* __restrict__ owtb) {
    __shared__ float lds[20 * 257];
    int bid = blockIdx.x, tid = threadIdx.x;
    if (bid < 1152) {                       // x -> xtb [b][p][64] bf16
        int b = bid / 576, p0 = (bid % 576) * 64;
        const float* src = x + b * CIN * HWd + p0;
        #pragma unroll
        for (int r = 0; r < 16; ++r) {
            int e = r * 256 + tid;          // e = c*64 + p
            int c = e >> 6, p = e & 63;
            lds[c * 65 + p] = src[c * HWd + p];
        }
        __syncthreads();
        ushort* dst = xtb + ((size_t)(b * HWd + p0)) * 64;
        #pragma unroll
        for (int r = 0; r < 16; ++r) {
            int e = r * 256 + tid;          // e = p*64 + c
            int p = e >> 6, c = e & 63;
            dst[e] = f2bf(lds[c * 65 + p]);
        }
    } else if (bid < 1728) {                // LO -> bf16 [b][p][24]
        int q = bid - 1152;
        int t = q / 288; q %= 288;
        int b = q / 144, p0 = (q % 144) * 256;
        const float* src = (t == 0 ? inLO : outLO) + b * NCh * HWd + p0;
        ushort* dst = (t == 0 ? inLOb : outLOb) + ((size_t)(b * HWd + p0)) * NCP;
        #pragma unroll
        for (int r = 0; r < 20; ++r) {
            int e = r * 256 + tid;          // e = n*256 + p
            int n = e >> 8, p = e & 255;
            lds[n * 257 + p] = src[n * HWd + p];
        }
        __syncthreads();
        #pragma unroll
        for (int r = 0; r < 24; ++r) {
            int e = r * 256 + tid;          // e = p*24 + n
            int p = e / NCP, n = e - p * NCP;
            dst[e] = (n < NCh) ? f2bf(lds[n * 257 + p]) : (ushort)0;
        }
    } else if (bid < 1872) {                // weight -> wtb B-frag
        int f = (bid - 1728) * 256 + tid;   // [tap][nt4][kt2][lane64][e8]
        int e = f & 7, lane = (f >> 3) & 63;
        int kt = (f >> 9) & 1, nt = (f >> 10) & 3, tap = f >> 12;
        int o = nt * 16 + (lane & 15);
        int c = kt * 32 + (lane >> 4) * 8 + e;
        wtb[f] = f2bf(w[(o * CIN + c) * Kk + tap]);
    } else {                                // off_w -> owtb (oc padded to 32)
        int f = (bid - 1872) * 256 + tid;   // [tap][nt2][kt2][lane64][e8] = 18432
        if (f < 18432) {
            int e = f & 7, lane = (f >> 3) & 63;
            int kt = (f >> 9) & 1, nt = (f >> 10) & 1, tap = f >> 11;
            int oc = nt * 16 + (lane & 15);
            int c = kt * 32 + (lane >> 4) * 8 + e;
            owtb[f] = (oc < 18) ? f2bf(off_w[(oc * CIN + c) * Kk + tap]) : (ushort)0;
        }
    }
}

// ---------------- k1: offset conv as MFMA GEMM ----------------
__global__ __launch_bounds__(256) void k1_gemm(const ushort* __restrict__ xtb,
        const ushort* __restrict__ owtb, const float* __restrict__ off_b,
        float* __restrict__ off) {
    int tid = threadIdx.x, bid = blockIdx.x;
    int jt = bid % 3, i = (bid / 3) % Hd, b = bid / (3 * Hd);
    int j0 = jt * 64;
    int lane = tid & 63, wv = tid >> 6;
    int m = lane & 15;
    int ch8 = lane >> 4;
    int j = j0 + wv * 16 + m;
    const ushort* xb = xtb + (size_t)b * HWd * 64;

    float bv0 = off_b[m];
    float bv1 = (m < 2) ? off_b[16 + m] : 0.f;
    f32x4 acc0 = (f32x4){bv0, bv0, bv0, bv0};
    f32x4 acc1 = (f32x4){bv1, bv1, bv1, bv1};
    short8 zero8 = {0, 0, 0, 0, 0, 0, 0, 0};

    #pragma unroll
    for (int t = 0; t < 9; ++t) {
        int yy = i + t / 3 - 1;
        int xx = j + t % 3 - 1;
        bool ok = (yy >= 0) && (yy < Hd) && (xx >= 0) && (xx < Wd);
        int yc = min(max(yy, 0), Hd - 1), xc = min(max(xx, 0), Wd - 1);
        const ushort* rowp = xb + (size_t)(yc * Wd + xc) * 64 + ch8 * 8;
        short8 a0 = *(const short8*)rowp;
        short8 a1 = *(const short8*)(rowp + 32);
        a0 = ok ? a0 : zero8;
        a1 = ok ? a1 : zero8;
        const ushort* wb = owtb + ((size_t)t << 11);
        short8 b00 = *(const short8*)(wb + (lane << 3));
        short8 b01 = *(const short8*)(wb + 512 + (lane << 3));
        short8 b10 = *(const short8*)(wb + 1024 + (lane << 3));
        short8 b11 = *(const short8*)(wb + 1536 + (lane << 3));
        acc0 = __builtin_amdgcn_mfma_f32_16x16x32_bf16(a0, b00, acc0, 0, 0, 0);
        acc0 = __builtin_amdgcn_mfma_f32_16x16x32_bf16(a1, b01, acc0, 0, 0, 0);
        acc1 = __builtin_amdgcn_mfma_f32_16x16x32_bf16(a0, b10, acc1, 0, 0, 0);
        acc1 = __builtin_amdgcn_mfma_f32_16x16x32_bf16(a1, b11, acc1, 0, 0, 0);
    }

    int prow = j0 + wv * 16 + (lane >> 4) * 4;
    int oc = lane & 15;
    float* ob = off + (size_t)b * 18 * HWd + i * Wd;
    #pragma unroll
    for (int r = 0; r < 4; ++r)
        ob[oc * HWd + prow + r] = acc0[r];
    if (oc < 2) {
        #pragma unroll
        for (int r = 0; r < 4; ++r)
            ob[(16 + oc) * HWd + prow + r] = acc1[r];
    }
}

// ---------------- k2: mask + sample-record generation ----------------
// Per (b,k,p): compute mask (border-clamped bilinear over LO, dot outLO),
// then the MAIN-conv bilinear coords/weights (zero-pad), premultiply by
// mask, and emit one 16B record {y0,y1,x0,x1:u16; w00,w01,w10,w11:f16}.
__global__ __launch_bounds__(256) void k2_mask(const ushort* __restrict__ inLOb,
        const ushort* __restrict__ outLOb, const float* __restrict__ off,
        uint4* __restrict__ rec) {
    int t = blockIdx.x * 256 + threadIdx.x;     // (b,k,p)
    int p = t % HWd;
    int k = (t / HWd) % Kk;
    int b = t / (Kk * HWd);
    int j = p % Wd, i = p / Wd;
    float offy = off[(b * 18 + 2 * k) * HWd + p];
    float offx = off[(b * 18 + 2 * k + 1) * HWd + p];

    // ---- mask: border-clamped bilinear over inLO, dot with outLO ----
    float py = (float)(i + (k / 3)) + offy - 95.5f;
    float px = (float)(j + (k % 3)) + offx - 95.5f;
    py = fminf(fmaxf(py, 0.f), 191.f);
    px = fminf(fmaxf(px, 0.f), 191.f);
    float y0f = floorf(py), x0f = floorf(px);
    float ly = py - y0f, lx = px - x0f;
    int y0 = (int)y0f, x0 = (int)x0f;
    int y1 = min(y0 + 1, Hd - 1), x1 = min(x0 + 1, Wd - 1);
    float w00 = (1.f - ly) * (1.f - lx);
    float w01 = (1.f - ly) * lx;
    float w10 = ly * (1.f - lx);
    float w11 = ly * lx;
    const short8* L00 = (const short8*)(inLOb + (size_t)(b * HWd + y0 * Wd + x0) * NCP);
    const short8* L01 = (const short8*)(inLOb + (size_t)(b * HWd + y0 * Wd + x1) * NCP);
    const short8* L10 = (const short8*)(inLOb + (size_t)(b * HWd + y1 * Wd + x0) * NCP);
    const short8* L11 = (const short8*)(inLOb + (size_t)(b * HWd + y1 * Wd + x1) * NCP);
    const short8* O  = (const short8*)(outLOb + (size_t)(b * HWd + p) * NCP);
    float acc = 0.f;
    #pragma unroll
    for (int n3 = 0; n3 < 3; ++n3) {
        short8 a = L00[n3], bb = L01[n3], c = L10[n3], d = L11[n3], o = O[n3];
        #pragma unroll
        for (int e = 0; e < 8; ++e) {
            float s = w00 * bf2f((ushort)a[e]) + w01 * bf2f((ushort)bb[e])
                    + w10 * bf2f((ushort)c[e]) + w11 * bf2f((ushort)d[e]);
            acc += s * bf2f((ushort)o[e]);
        }
    }

    // ---- main-conv bilinear record (zero-pad semantics) ----
    float py2 = (float)(i - 1 + (k / 3)) + offy;
    float px2 = (float)(j - 1 + (k % 3)) + offx;
    float y0f2 = floorf(py2), x0f2 = floorf(px2);
    float ly2 = py2 - y0f2, lx2 = px2 - x0f2;
    int yA = (int)y0f2, xA = (int)x0f2;
    int yB = yA + 1, xB = xA + 1;
    bool vy0 = (yA >= 0 && yA < Hd), vy1 = (yB >= 0 && yB < Hd);
    bool vx0 = (xA >= 0 && xA < Wd), vx1 = (xB >= 0 && xB < Wd);
    float W00 = (vy0 && vx0) ? (1.f - ly2) * (1.f - lx2) * acc : 0.f;
    float W01 = (vy0 && vx1) ? (1.f - ly2) * lx2 * acc : 0.f;
    float W10 = (vy1 && vx0) ? ly2 * (1.f - lx2) * acc : 0.f;
    float W11 = (vy1 && vx1) ? ly2 * lx2 * acc : 0.f;
    int y0c = min(max(yA, 0), Hd - 1), y1c = min(max(yB, 0), Hd - 1);
    int x0c = min(max(xA, 0), Wd - 1), x1c = min(max(xB, 0), Wd - 1);
    uint4 r;
    r.x = (unsigned)y0c | ((unsigned)y1c << 16);
    r.y = (unsigned)x0c | ((unsigned)x1c << 16);
    r.z = (unsigned)f2h(W00) | ((unsigned)f2h(W01) << 16);
    r.w = (unsigned)f2h(W10) | ((unsigned)f2h(W11) << 16);
    rec[(size_t)(b * Kk + k) * HWd + p] = r;
}

// ---------------- k3: deformable conv, bf16 MFMA GEMM ----------------
// Staging per round: 1x dwordx4 record load -> 4 coalesced 16B gathers.
__global__ __launch_bounds__(256) void k3_part(const ushort* __restrict__ xtb,
        const uint4* __restrict__ rec, const ushort* __restrict__ wtb,
        ushort* __restrict__ part) {
    __shared__ __align__(16) ushort A_lds[4 * 2 * 64 * 8];   // 8 KB
    int tid = threadIdx.x;
    int bid = blockIdx.x;
    int h = bid >= NTILE;           // taps [0,5) or [5,9)
    int tb = bid - (h ? NTILE : 0);
    int t0 = h ? 5 : 0, t1 = h ? 9 : 5;
    int jt = tb % 3, i = (tb / 3) % Hd, b = tb / (3 * Hd);
    int j0 = jt * 64;

    int lane = tid & 63;
    int wv_id = tid >> 6;
    int wm = wv_id >> 1;
    int wn = wv_id & 1;

    int pxo = lane & 7;
    int chunk = lane >> 3;
    int kt_s = chunk >> 2;
    int ksub = chunk & 3;
    const ushort* xb = xtb + (size_t)b * HWd * 64;

    f32x4 acc[2][2];
    #pragma unroll
    for (int mi = 0; mi < 2; ++mi)
        #pragma unroll
        for (int ni = 0; ni < 2; ++ni)
            acc[mi][ni] = (f32x4){0.f, 0.f, 0.f, 0.f};

    for (int t = t0; t < t1; ++t) {
        short8 bf[2][2];
        #pragma unroll
        for (int kt = 0; kt < 2; ++kt)
            #pragma unroll
            for (int ni = 0; ni < 2; ++ni) {
                int nt = wn * 2 + ni;
                bf[kt][ni] = *(const short8*)(wtb +
                    ((((t * 4 + nt) * 2 + kt) * 64 + lane) << 3));
            }

        const uint4* recb = rec + (size_t)(b * Kk + t) * HWd + i * Wd + j0;
        #pragma unroll
        for (int r = 0; r < 2; ++r) {
            int px_loc = (wv_id << 4) + (r << 3) + pxo;
            uint4 rc = recb[px_loc];
            int y0 = rc.x & 0xffff, y1 = rc.x >> 16;
            int x0 = rc.y & 0xffff, x1 = rc.y >> 16;
            float w00 = h2f((ushort)(rc.z & 0xffff));
            float w01 = h2f((ushort)(rc.z >> 16));
            float w10 = h2f((ushort)(rc.w & 0xffff));
            float w11 = h2f((ushort)(rc.w >> 16));
            const short8* g0p = (const short8*)(xb + (size_t)(y0 * Wd + x0) * 64 + chunk * 8);
            const short8* g1p = (const short8*)(xb + (size_t)(y0 * Wd + x1) * 64 + chunk * 8);
            const short8* g2p = (const short8*)(xb + (size_t)(y1 * Wd + x0) * 64 + chunk * 8);
            const short8* g3p = (const short8*)(xb + (size_t)(y1 * Wd + x1) * 64 + chunk * 8);
            short8 g0 = *g0p, g1 = *g1p, g2 = *g2p, g3 = *g3p;
            short8 pk;
            #pragma unroll
            for (int e = 0; e < 8; ++e) {
                float s = w00 * bf2f((ushort)g0[e]) + w01 * bf2f((ushort)g1[e])
                        + w10 * bf2f((ushort)g2[e]) + w11 * bf2f((ushort)g3[e]);
                pk[e] = (short)f2bf(s);
            }
            *(short8*)&A_lds[(((wv_id * 2 + kt_s) * 64 + ksub * 16 +
                               ((r << 3) + pxo)) << 3)] = pk;
        }
        __syncthreads();

        #pragma unroll
        for (int kt = 0; kt < 2; ++kt) {
            #pragma unroll
            for (int mi = 0; mi < 2; ++mi) {
                int mt2 = wm * 2 + mi;
                short8 af = *(const short8*)&A_lds[(((mt2 * 2 + kt) * 64 + lane) << 3)];
                acc[mi][0] = __builtin_amdgcn_mfma_f32_16x16x32_bf16(
                                 af, bf[kt][0], acc[mi][0], 0, 0, 0);
                acc[mi][1] = __builtin_amdgcn_mfma_f32_16x16x32_bf16(
                                 af, bf[kt][1], acc[mi][1], 0, 0, 0);
            }
        }
        __syncthreads();
    }

    // write partial tile as bf16: part[(h*NTILE+tb)*4096 + o*64 + p]
    ushort* pb = part + ((size_t)(h * NTILE + tb) << 12);
    int colo = lane & 15;
    int rb = (lane >> 4) * 4;
    #pragma unroll
    for (int ni = 0; ni < 2; ++ni) {
        int o = wn * 32 + ni * 16 + colo;
        #pragma unroll
        for (int mi = 0; mi < 2; ++mi) {
            int p0 = wm * 32 + mi * 16 + rb;
            ushort4 s;
            s.x = f2bf(acc[mi][ni][0]);
            s.y = f2bf(acc[mi][ni][1]);
            s.z = f2bf(acc[mi][ni][2]);
            s.w = f2bf(acc[mi][ni][3]);
            *(ushort4*)(pb + o * 64 + p0) = s;
        }
    }
}

// ---------------- k4: reduce bf16 halves + bias -> out ----------------
__global__ __launch_bounds__(256) void k4_reduce(const ushort* __restrict__ part,
        const float* __restrict__ bias, float* __restrict__ out) {
    int g = blockIdx.x * 256 + threadIdx.x;     // short8 index, NTILE*512 total
    int tile = g >> 9;
    int wi = g & 511;
    int o = wi >> 3;
    int p0 = (wi & 7) << 3;
    const short8* pp = (const short8*)part;
    short8 a = pp[g];
    short8 c = pp[g + NTILE * 512];
    float bv = bias[o];
    int jt = tile % 3, i = (tile / 3) % Hd, b = tile / (3 * Hd);
    float* op = out + ((size_t)(b * COUT + o) * HWd) + i * Wd + jt * 64 + p0;
    float4 r0, r1;
    r0.x = bf2f((ushort)a[0]) + bf2f((ushort)c[0]) + bv;
    r0.y = bf2f((ushort)a[1]) + bf2f((ushort)c[1]) + bv;
    r0.z = bf2f((ushort)a[2]) + bf2f((ushort)c[2]) + bv;
    r0.w = bf2f((ushort)a[3]) + bf2f((ushort)c[3]) + bv;
    r1.x = bf2f((ushort)a[4]) + bf2f((ushort)c[4]) + bv;
    r1.y = bf2f((ushort)a[5]) + bf2f((ushort)c[5]) + bv;
    r1.z = bf2f((ushort)a[6]) + bf2f((ushort)c[6]) + bv;
    r1.w = bf2f((ushort)a[7]) + bf2f((ushort)c[7]) + bv;
    *(float4*)op = r0;
    *(float4*)(op + 4) = r1;
}

extern "C" void kernel_launch(void* const* d_in, const int* in_sizes, int n_in,
                              void* d_out, int out_size, void* d_ws, size_t ws_size,
                              hipStream_t stream) {
    const float* x      = (const float*)d_in[0];
    const float* inLO   = (const float*)d_in[1];
    const float* outLO  = (const float*)d_in[2];
    const float* weight = (const float*)d_in[3];
    const float* bias   = (const float*)d_in[4];
    const float* off_w  = (const float*)d_in[5];
    const float* off_b  = (const float*)d_in[6];
    float* out = (float*)d_out;

    // workspace layout (rec first for 16B alignment)
    uint4*  rec    = (uint4*)d_ws;                          // 663552 * 16B
    ushort* part   = (ushort*)(rec + (size_t)Bn * Kk * HWd);// 2*1152*4096 bf16
    float*  off    = (float*)(part + (size_t)2 * NTILE * 4096); // 2*18*36864 f
    ushort* wtb    = (ushort*)(off + (size_t)Bn * 18 * HWd);    // 36864
    ushort* owtb   = wtb + 36864;                               // 18432
    ushort* xtb    = owtb + 18432;                              // 2*36864*64
    ushort* inLOb  = xtb + (size_t)Bn * HWd * CIN;              // 2*36864*24
    ushort* outLOb = inLOb + (size_t)Bn * HWd * NCP;

    kT<<<1944, 256, 0, stream>>>(x, inLO, outLO, weight, off_w,
                                 xtb, inLOb, outLOb, wtb, owtb);
    k1_gemm<<<NTILE, 256, 0, stream>>>(xtb, owtb, off_b, off);
    k2_mask<<<2592, 256, 0, stream>>>(inLOb, outLOb, off, rec);
    k3_part<<<2 * NTILE, 256, 0, stream>>>(xtb, rec, wtb, part);
    k4_reduce<<<2304, 256, 0, stream>>>(part, bias, out);
}